// Round 15
// baseline (2677.365 us; speedup 1.0000x reference)
//
#include <hip/hip_runtime.h>

#define INPUT 64
#define HID 256
#define BATCH 128
#define TSTEPS 1000
#define KTOT 320            // 256 (h) + 64 (x)

typedef __bf16 bf16_t;
typedef __bf16 bf16x8 __attribute__((ext_vector_type(8)));
typedef float  f32x4  __attribute__((ext_vector_type(4)));

// ---- ws layout (bytes) ----
#define WPACK_OFF   0
#define WPACK_BYTES (1024 * KTOT * 2)            // 655360
#define BIAS_OFF    (WPACK_OFF + WPACK_BYTES)
#define BIAS_BYTES  (1024 * 4)
#define EXCH_OFF    (BIAS_OFF + BIAS_BYTES)      // 32 blocks x 2 parity x 1024 bf16
#define EXCH_BYTES  (32 * 2 * 1024 * 2)          // 131072
#define FLAG_OFF    (EXCH_OFF + EXCH_BYTES)      // 32 flags, 256B apart

// ---- dynamic LDS layout (bytes) ----
// wlds: 256 rows (4 gates x 64 cols) x 264 bf16 (256 K + 8 pad) = 135168
// hxx : 2 parity x 16 rows x 328 bf16                           =  20992
#define WLDS_ROWP   264
#define WLDS_BYTES  (256 * WLDS_ROWP * 2)
#define HXX_ELEMS   (16 * 328)
#define SMEM_BYTES  (WLDS_BYTES + 2 * HXX_ELEMS * 2)   // 156160 < 160 KiB

__global__ void lstm_prep(
    const float* __restrict__ Wii, const float* __restrict__ Wif,
    const float* __restrict__ Wig, const float* __restrict__ Wio,
    const float* __restrict__ Whi, const float* __restrict__ Whf,
    const float* __restrict__ Whg, const float* __restrict__ Who,
    const float* __restrict__ bii, const float* __restrict__ bif,
    const float* __restrict__ big, const float* __restrict__ bio,
    const float* __restrict__ bhi, const float* __restrict__ bhf,
    const float* __restrict__ bhg, const float* __restrict__ bho,
    bf16_t* __restrict__ wpack, float* __restrict__ bias,
    int* __restrict__ flags)
{
    int id = blockIdx.x * 256 + threadIdx.x;
    if (id < 1024 * KTOT) {
        int n = id / KTOT, k = id % KTOT;
        int g = n >> 8, j = n & 255;
        const float* Wh = (g == 0) ? Whi : (g == 1) ? Whf : (g == 2) ? Whg : Who;
        const float* Wi = (g == 0) ? Wii : (g == 1) ? Wif : (g == 2) ? Wig : Wio;
        float v = (k < HID) ? Wh[j * HID + k] : Wi[j * INPUT + (k - HID)];
        wpack[id] = (bf16_t)v;
    }
    if (id < 1024) {
        int g = id >> 8, j = id & 255;
        const float* bi = (g == 0) ? bii : (g == 1) ? bif : (g == 2) ? big : bio;
        const float* bh = (g == 0) ? bhi : (g == 1) ? bhf : (g == 2) ? bhg : bho;
        bias[id] = bi[j] + bh[j];
    }
    if (id < 32)
        __hip_atomic_store(flags + id * 64, 0, __ATOMIC_RELAXED, __HIP_MEMORY_SCOPE_AGENT);
}

__device__ __forceinline__ float sigmoid_f(float v) {
    return 1.0f / (1.0f + __expf(-v));
}
__device__ __forceinline__ float tanh_f(float v) {
    return 1.0f - 2.0f / (__expf(2.0f * v) + 1.0f);
}

// 32 blocks x 256 threads. group = bid&7 (16 batch rows), qtr = bid>>3
// (64 cols x all 4 gates). Wave w owns cols [w*16,w*16+16), ALL 4 gates.
// h-weights LDS-RESIDENT (staged once; 32 ds_read_b128/wave/step, layout
// conflict-free); x-weights in 32 registers (R4-proven scale). All builtin
// MFMAs. sc0 sc1 device-coherent exchange + in-register epilogue: R12 verbatim.
__global__ __launch_bounds__(256) __attribute__((amdgpu_waves_per_eu(1, 1)))
void lstm_main(
    const float* __restrict__ x, const bf16_t* __restrict__ wpack,
    const float* __restrict__ bias_g, float* __restrict__ out,
    bf16_t* __restrict__ exch, int* __restrict__ flags)
{
    extern __shared__ __align__(16) char smem[];
    bf16_t* wlds = (bf16_t*)smem;                          // [256][264]
    bf16_t* hxx0 = (bf16_t*)(smem + WLDS_BYTES);           // [2][16*328]

    const int bid   = blockIdx.x;
    const int group = bid & 7;
    const int qtr   = bid >> 3;          // 0..3
    const int tid   = threadIdx.x;
    const int w     = tid >> 6;          // wave 0..3
    const int l     = tid & 63;
    const int col   = l & 15;
    const int kb    = l >> 4;            // 0..3

    const int jblk  = w * 16 + col;            // 0..63 within quarter
    const int jglob = qtr * 64 + jblk;         // 0..255

    // ---- stage h-weights into LDS (once): thread tid copies row tid ----
    {
        const int r = tid;                               // r = g*64 + jl
        const bf16_t* src = wpack + (size_t)((r >> 6) * 256 + qtr * 64 + (r & 63)) * KTOT;
        bf16_t* dst = wlds + r * WLDS_ROWP;
#pragma unroll
        for (int k = 0; k < 256; k += 8)
            *(f32x4*)(dst + k) = *(const f32x4*)(src + k);
    }

    // ---- x-slice weights in registers: 4 gates x 2 = 8 frags = 32 VGPRs ----
    bf16x8 bX[4][2];
#pragma unroll
    for (int g = 0; g < 4; ++g) {
        const bf16_t* wrow = wpack + (size_t)(g * 256 + jglob) * KTOT;
#pragma unroll
        for (int i = 0; i < 2; ++i)
            bX[g][i] = *(const bf16x8*)(wrow + (8 + i) * 32 + kb * 8);
    }
#pragma unroll
    for (int g = 0; g < 4; ++g)
#pragma unroll
        for (int i = 0; i < 2; ++i)
            asm volatile("" : "+v"(bX[g][i]));

    float bias_r[4];
#pragma unroll
    for (int g = 0; g < 4; ++g)
        bias_r[g] = bias_g[g * 256 + jglob];

    float c_st[4] = {0.f, 0.f, 0.f, 0.f};

    int* flag_me = flags + bid * 64;
    // partner fetch: waves 0..2 fetch partner w; lane -> (row, 16-col slice)
    const int pqtr   = (qtr + 1 + w) & 3;            // valid for w<3
    const int pbid   = pqtr * 8 + group;
    const int* flag_pn = flags + pbid * 64;
    const int prow   = l >> 2;
    const int pc16   = (l & 3) * 16;

    // x staging: thread -> (row xr, 4 f32 at xi0)
    const int xr  = tid >> 4;
    const int xi0 = (tid & 15) * 4;
    const float* xbase = x + (size_t)(group * 16 + xr) * (TSTEPS * INPUT) + xi0;

    // prologue: x_0 -> hxx[0], x_1 -> regs
    {
        float4 v = *(const float4*)(xbase);
        bf16_t* d = hxx0 + xr * 328 + 256 + xi0;
        d[0] = (bf16_t)v.x; d[1] = (bf16_t)v.y; d[2] = (bf16_t)v.z; d[3] = (bf16_t)v.w;
    }
    float4 xv = *(const float4*)(xbase + INPUT);
    __syncthreads();

#pragma unroll 1
    for (int t = 0; t < TSTEPS; ++t) {
        const int cur = t & 1;
        const int nxt = cur ^ 1;
        bf16_t* hcur = hxx0 + cur * HXX_ELEMS;
        bf16_t* hnxt = hxx0 + nxt * HXX_ELEMS;

        // ---- P1: stage x_{t+1} -> hxx[nxt]; fetch 3 partner pubs -> hxx[cur]
        if (t + 1 < TSTEPS) {
            bf16_t* d = hnxt + xr * 328 + 256 + xi0;
            d[0] = (bf16_t)xv.x; d[1] = (bf16_t)xv.y; d[2] = (bf16_t)xv.z; d[3] = (bf16_t)xv.w;
        }
        if (t + 2 < TSTEPS)
            xv = *(const float4*)(xbase + (size_t)(t + 2) * INPUT);
        if (t > 0 && w < 3) {
            // self-spin (relaxed, agent)
            while (__hip_atomic_load(flag_pn, __ATOMIC_RELAXED, __HIP_MEMORY_SCOPE_AGENT) < t) {}
            // device-coherent read; load+wait in ONE asm block (R13 lesson)
            const bf16_t* src = exch + ((size_t)pbid * 2 + ((t - 1) & 1)) * 1024
                              + prow * 64 + pc16;
            f32x4 v0, v1;
            asm volatile(
                "global_load_dwordx4 %0, %2, off sc0 sc1\n\t"
                "global_load_dwordx4 %1, %3, off sc0 sc1\n\t"
                "s_waitcnt vmcnt(0)"
                : "=&v"(v0), "=&v"(v1)
                : "v"(src), "v"(src + 8)
                : "memory");
            bf16_t* dst = hcur + prow * 328 + pqtr * 64 + pc16;
            *(f32x4*)(dst)     = v0;
            *(f32x4*)(dst + 8) = v1;
        }
        __syncthreads();                                   // B1: hxx[cur] complete

        // ---- P2: 40 builtin MFMAs; h-B from LDS, x-B from regs ----
        f32x4 acc[4];
#pragma unroll
        for (int g = 0; g < 4; ++g)
            acc[g] = (f32x4){bias_r[g], bias_r[g], bias_r[g], bias_r[g]};

        const bf16_t* arow = hcur + col * 328 + kb * 8;
        {
            bf16x8 a8 = *(const bf16x8*)(arow + 8 * 32);
            bf16x8 a9 = *(const bf16x8*)(arow + 9 * 32);
#pragma unroll
            for (int g = 0; g < 4; ++g) {
                acc[g] = __builtin_amdgcn_mfma_f32_16x16x32_bf16(a8, bX[g][0], acc[g], 0, 0, 0);
                acc[g] = __builtin_amdgcn_mfma_f32_16x16x32_bf16(a9, bX[g][1], acc[g], 0, 0, 0);
            }
        }
        if (t > 0) {
            const bf16_t* brow = wlds + jblk * WLDS_ROWP + kb * 8;   // gate stride 64 rows
#pragma unroll
            for (int ks = 0; ks < 8; ++ks) {
                bf16x8 a = *(const bf16x8*)(arow + ks * 32);
#pragma unroll
                for (int g = 0; g < 4; ++g) {
                    bf16x8 b = *(const bf16x8*)(brow + (g * 64) * WLDS_ROWP + ks * 32);
                    acc[g] = __builtin_amdgcn_mfma_f32_16x16x32_bf16(a, b, acc[g], 0, 0, 0);
                }
            }
        }

        // ---- P3: in-register epilogue; h -> hxx[nxt] own cols + pub (sc1) ----
        bf16_t* pub = exch + ((size_t)bid * 2 + cur) * 1024;
        float hv[4];
#pragma unroll
        for (int r = 0; r < 4; ++r) {
            float gi = sigmoid_f(acc[0][r]);
            float gf = sigmoid_f(acc[1][r]);
            float gg = tanh_f(acc[2][r]);
            float go = sigmoid_f(acc[3][r]);
            float c  = gf * c_st[r] + gi * gg;
            c_st[r]  = c;
            float h  = go * tanh_f(c);
            hv[r]    = h;
            bf16_t hb = (bf16_t)h;
            const int row = kb * 4 + r;
            hnxt[row * 328 + jglob] = hb;                  // own A for next step
            // device-coherent pub store (write-through to MALL)
            unsigned int hbits = (unsigned int)__builtin_bit_cast(unsigned short, hb);
            const bf16_t* paddr = pub + row * 64 + jblk;
            asm volatile("global_store_short %0, %1, off sc0 sc1"
                         :: "v"(paddr), "v"(hbits) : "memory");
        }
        // drain the asm stores (compiler doesn't track inline-asm VMEM)
        asm volatile("s_waitcnt vmcnt(0)" ::: "memory");
        __syncthreads();                                   // B0: all pubs at MALL
        if (tid == 0)
            __hip_atomic_store(flag_me, t + 1, __ATOMIC_RELAXED, __HIP_MEMORY_SCOPE_AGENT);

        // out stores AFTER release (drain overlaps next step's spin)
#pragma unroll
        for (int r = 0; r < 4; ++r) {
            const int row = kb * 4 + r;
            const int bg  = group * 16 + row;
            out[((size_t)bg * TSTEPS + t) * HID + jglob] = hv[r];
        }
        if (t == TSTEPS - 1) {
            float* hn = out + (size_t)BATCH * TSTEPS * HID;
            float* cn = hn + (size_t)BATCH * HID;
#pragma unroll
            for (int r = 0; r < 4; ++r) {
                const int row = kb * 4 + r;
                const int bg  = group * 16 + row;
                hn[(size_t)bg * HID + jglob] = hv[r];
                cn[(size_t)bg * HID + jglob] = c_st[r];
            }
        }
    }
}

extern "C" void kernel_launch(void* const* d_in, const int* in_sizes, int n_in,
                              void* d_out, int out_size, void* d_ws, size_t ws_size,
                              hipStream_t stream)
{
    (void)in_sizes; (void)n_in; (void)out_size; (void)ws_size;
    const float* x   = (const float*)d_in[0];
    const float* Wii = (const float*)d_in[1];
    const float* bii = (const float*)d_in[2];
    const float* Wif = (const float*)d_in[3];
    const float* bif = (const float*)d_in[4];
    const float* Wig = (const float*)d_in[5];
    const float* big = (const float*)d_in[6];
    const float* Wio = (const float*)d_in[7];
    const float* bio = (const float*)d_in[8];
    const float* Whi = (const float*)d_in[9];
    const float* bhi = (const float*)d_in[10];
    const float* Whf = (const float*)d_in[11];
    const float* bhf = (const float*)d_in[12];
    const float* Whg = (const float*)d_in[13];
    const float* bhg = (const float*)d_in[14];
    const float* Who = (const float*)d_in[15];
    const float* bho = (const float*)d_in[16];

    char* ws = (char*)d_ws;
    bf16_t* wpack = (bf16_t*)(ws + WPACK_OFF);
    float*  bias  = (float*)(ws + BIAS_OFF);
    bf16_t* exch  = (bf16_t*)(ws + EXCH_OFF);
    int*    flags = (int*)(ws + FLAG_OFF);

    // allow >64 KiB dynamic LDS (no-op if already permitted)
    static bool attr_set = false;
    if (!attr_set) {
        (void)hipFuncSetAttribute(reinterpret_cast<const void*>(lstm_main),
                                  hipFuncAttributeMaxDynamicSharedMemorySize,
                                  SMEM_BYTES);
        attr_set = true;
    }

    lstm_prep<<<(1024 * KTOT + 255) / 256, 256, 0, stream>>>(
        Wii, Wif, Wig, Wio, Whi, Whf, Whg, Who,
        bii, bif, big, bio, bhi, bhf, bhg, bho,
        wpack, bias, flags);

    lstm_main<<<32, 256, SMEM_BYTES, stream>>>(
        x, wpack, bias, (float*)d_out, exch, flags);
}

// Round 16
// 2505.200 us; speedup vs baseline: 1.0687x; 1.0687x over previous
//
#include <hip/hip_runtime.h>

#define INPUT 64
#define HID 256
#define BATCH 128
#define TSTEPS 1000
#define KTOT 320            // 256 (h) + 64 (x)

typedef __bf16 bf16_t;
typedef __bf16 bf16x8 __attribute__((ext_vector_type(8)));
typedef float  f32x4  __attribute__((ext_vector_type(4)));
typedef unsigned int       u32;
typedef unsigned long long u64;

// ---- ws layout (bytes) ----
#define WPACK_OFF   0
#define WPACK_BYTES (1024 * KTOT * 2)            // 655360
#define BIAS_OFF    (WPACK_OFF + WPACK_BYTES)
#define BIAS_BYTES  (1024 * 4)
#define EXCH_OFF    (BIAS_OFF + BIAS_BYTES)
// tagged exchange: 32 blocks x 2 parity x (16 rows x 64 cols) u32
// word = h_bf16_bits | (step+1) << 16   (data IS the flag)
#define EXCH_WORDS  (32 * 2 * 1024)
#define EXCH_BYTES  (EXCH_WORDS * 4)             // 262144

// ---- dynamic LDS layout ----
#define WLDS_ROWP   264
#define WLDS_BYTES  (256 * WLDS_ROWP * 2)        // 135168
#define HXX_ELEMS   (16 * 328)
#define SMEM_BYTES  (WLDS_BYTES + 2 * HXX_ELEMS * 2)   // 156160 < 160 KiB

__global__ void lstm_prep(
    const float* __restrict__ Wii, const float* __restrict__ Wif,
    const float* __restrict__ Wig, const float* __restrict__ Wio,
    const float* __restrict__ Whi, const float* __restrict__ Whf,
    const float* __restrict__ Whg, const float* __restrict__ Who,
    const float* __restrict__ bii, const float* __restrict__ bif,
    const float* __restrict__ big, const float* __restrict__ bio,
    const float* __restrict__ bhi, const float* __restrict__ bhf,
    const float* __restrict__ bhg, const float* __restrict__ bho,
    bf16_t* __restrict__ wpack, float* __restrict__ bias,
    u32* __restrict__ exch)
{
    int id = blockIdx.x * 256 + threadIdx.x;
    if (id < 1024 * KTOT) {
        int n = id / KTOT, k = id % KTOT;
        int g = n >> 8, j = n & 255;
        const float* Wh = (g == 0) ? Whi : (g == 1) ? Whf : (g == 2) ? Whg : Who;
        const float* Wi = (g == 0) ? Wii : (g == 1) ? Wif : (g == 2) ? Wig : Wio;
        float v = (k < HID) ? Wh[j * HID + k] : Wi[j * INPUT + (k - HID)];
        wpack[id] = (bf16_t)v;
    }
    if (id < 1024) {
        int g = id >> 8, j = id & 255;
        const float* bi = (g == 0) ? bii : (g == 1) ? bif : (g == 2) ? big : bio;
        const float* bh = (g == 0) ? bhi : (g == 1) ? bhf : (g == 2) ? bhg : bho;
        bias[id] = bi[j] + bh[j];
    }
    // clear tagged exchange every launch (tag 0 matches no target >= 1):
    // makes graph replays deterministic (no stale-tag match across runs)
    if (id < EXCH_WORDS)
        __hip_atomic_store(exch + id, 0u, __ATOMIC_RELAXED, __HIP_MEMORY_SCOPE_SYSTEM);
}

__device__ __forceinline__ float sigmoid_f(float v) {
    return 1.0f / (1.0f + __expf(-v));
}
__device__ __forceinline__ float tanh_f(float v) {
    return 1.0f - 2.0f / (__expf(2.0f * v) + 1.0f);
}

// 32 blocks x 256 threads. group = bid&7 (16 batch rows), qtr = bid>>3
// (64 cols x all 4 gates). h-weights LDS-resident (R15-proven). Exchange is
// tagged-data through MALL via system-scope relaxed atomics: poll success
// delivers the payload in the same round trip (no separate flag+data trips).
__global__ __launch_bounds__(256) __attribute__((amdgpu_waves_per_eu(1, 1)))
void lstm_main(
    const float* __restrict__ x, const bf16_t* __restrict__ wpack,
    const float* __restrict__ bias_g, float* __restrict__ out,
    u32* __restrict__ exch)
{
    extern __shared__ __align__(16) char smem[];
    bf16_t* wlds = (bf16_t*)smem;                          // [256][264]
    bf16_t* hxx0 = (bf16_t*)(smem + WLDS_BYTES);           // [2][16*328]

    const int bid   = blockIdx.x;
    const int group = bid & 7;
    const int qtr   = bid >> 3;          // 0..3
    const int tid   = threadIdx.x;
    const int w     = tid >> 6;          // wave 0..3
    const int l     = tid & 63;
    const int col   = l & 15;
    const int kb    = l >> 4;            // 0..3

    const int jblk  = w * 16 + col;            // 0..63 within quarter
    const int jglob = qtr * 64 + jblk;         // 0..255

    // ---- stage h-weights into LDS (once): thread tid copies row tid ----
    {
        const int r = tid;                               // r = g*64 + jl
        const bf16_t* src = wpack + (size_t)((r >> 6) * 256 + qtr * 64 + (r & 63)) * KTOT;
        bf16_t* dst = wlds + r * WLDS_ROWP;
#pragma unroll
        for (int k = 0; k < 256; k += 8)
            *(f32x4*)(dst + k) = *(const f32x4*)(src + k);
    }

    // ---- x-slice weights in registers: 4 gates x 2 = 8 frags = 32 VGPRs ----
    bf16x8 bX[4][2];
#pragma unroll
    for (int g = 0; g < 4; ++g) {
        const bf16_t* wrow = wpack + (size_t)(g * 256 + jglob) * KTOT;
#pragma unroll
        for (int i = 0; i < 2; ++i)
            bX[g][i] = *(const bf16x8*)(wrow + (8 + i) * 32 + kb * 8);
    }
#pragma unroll
    for (int g = 0; g < 4; ++g)
#pragma unroll
        for (int i = 0; i < 2; ++i)
            asm volatile("" : "+v"(bX[g][i]));

    float bias_r[4];
#pragma unroll
    for (int g = 0; g < 4; ++g)
        bias_r[g] = bias_g[g * 256 + jglob];

    float c_st[4] = {0.f, 0.f, 0.f, 0.f};

    // partner fetch: waves 0..2 fetch partner w; lane covers 16 tagged words
    // (words l*16 .. l*16+15 of the 1024-word pub) -> row l>>2, cols (l&3)*16
    const int pqtr = (qtr + 1 + w) & 3;              // valid for w<3
    const int pbid = pqtr * 8 + group;
    const int prow = l >> 2;
    const int pc16 = (l & 3) * 16;

    // x staging: thread -> (row xr, 4 f32 at xi0)
    const int xr  = tid >> 4;
    const int xi0 = (tid & 15) * 4;
    const float* xbase = x + (size_t)(group * 16 + xr) * (TSTEPS * INPUT) + xi0;

    // prologue: x_0 -> hxx[0], x_1 -> regs
    {
        float4 v = *(const float4*)(xbase);
        bf16_t* d = hxx0 + xr * 328 + 256 + xi0;
        d[0] = (bf16_t)v.x; d[1] = (bf16_t)v.y; d[2] = (bf16_t)v.z; d[3] = (bf16_t)v.w;
    }
    float4 xv = *(const float4*)(xbase + INPUT);
    __syncthreads();

#pragma unroll 1
    for (int t = 0; t < TSTEPS; ++t) {
        const int cur = t & 1;
        const int nxt = cur ^ 1;
        bf16_t* hcur = hxx0 + cur * HXX_ELEMS;
        bf16_t* hnxt = hxx0 + nxt * HXX_ELEMS;

        // ---- A: x + own-quarter MFMAs (gives producers time to publish) ----
        f32x4 acc[4];
#pragma unroll
        for (int g = 0; g < 4; ++g)
            acc[g] = (f32x4){bias_r[g], bias_r[g], bias_r[g], bias_r[g]};

        const bf16_t* arow = hcur + col * 328 + kb * 8;
        const bf16_t* brow = wlds + jblk * WLDS_ROWP + kb * 8;
        {
            bf16x8 a8 = *(const bf16x8*)(arow + 8 * 32);
            bf16x8 a9 = *(const bf16x8*)(arow + 9 * 32);
#pragma unroll
            for (int g = 0; g < 4; ++g) {
                acc[g] = __builtin_amdgcn_mfma_f32_16x16x32_bf16(a8, bX[g][0], acc[g], 0, 0, 0);
                acc[g] = __builtin_amdgcn_mfma_f32_16x16x32_bf16(a9, bX[g][1], acc[g], 0, 0, 0);
            }
        }
        if (t > 0) {
#pragma unroll
            for (int i = 0; i < 2; ++i) {
                const int ks = 2 * qtr + i;
                bf16x8 a = *(const bf16x8*)(arow + ks * 32);
#pragma unroll
                for (int g = 0; g < 4; ++g) {
                    bf16x8 b = *(const bf16x8*)(brow + (g * 64) * WLDS_ROWP + ks * 32);
                    acc[g] = __builtin_amdgcn_mfma_f32_16x16x32_bf16(a, b, acc[g], 0, 0, 0);
                }
            }
        }

        // ---- B: stage x_{t+1} -> hxx[nxt]; prefetch x_{t+2} ----
        if (t + 1 < TSTEPS) {
            bf16_t* d = hnxt + xr * 328 + 256 + xi0;
            d[0] = (bf16_t)xv.x; d[1] = (bf16_t)xv.y; d[2] = (bf16_t)xv.z; d[3] = (bf16_t)xv.w;
        }
        if (t + 2 < TSTEPS)
            xv = *(const float4*)(xbase + (size_t)(t + 2) * INPUT);

        // ---- C: poll tagged partner data (payload arrives with the tag) ----
        if (t > 0 && w < 3) {
            const u64* tp = (const u64*)(exch + ((size_t)pbid * 2 + ((t - 1) & 1)) * 1024)
                          + l * 8;
            const u32 want = (u32)t;
            u64 v[8];
            for (;;) {
                bool ok = true;
#pragma unroll
                for (int i = 0; i < 8; ++i)
                    v[i] = __hip_atomic_load(tp + i, __ATOMIC_RELAXED, __HIP_MEMORY_SCOPE_SYSTEM);
#pragma unroll
                for (int i = 0; i < 8; ++i) {
                    ok = ok && (((u32)(v[i] >> 16) & 0xFFFFu) == want);
                    ok = ok && (((u32)(v[i] >> 48)) == want);
                }
                if (ok) break;
            }
            u32 hp[8];
#pragma unroll
            for (int i = 0; i < 8; ++i)
                hp[i] = ((u32)v[i] & 0xFFFFu) | (((u32)(v[i] >> 32) & 0xFFFFu) << 16);
            bf16_t* dst = hcur + prow * 328 + pqtr * 64 + pc16;
            *(f32x4*)(dst)     = *(const f32x4*)&hp[0];
            *(f32x4*)(dst + 8) = *(const f32x4*)&hp[4];
        }
        __syncthreads();                                   // B1: hxx[cur] complete

        // ---- D: 24 partner-slice MFMAs ----
        if (t > 0) {
#pragma unroll
            for (int p = 0; p < 3; ++p) {
                const int pq = (qtr + 1 + p) & 3;
#pragma unroll
                for (int i = 0; i < 2; ++i) {
                    const int ks = 2 * pq + i;
                    bf16x8 a = *(const bf16x8*)(arow + ks * 32);
#pragma unroll
                    for (int g = 0; g < 4; ++g) {
                        bf16x8 b = *(const bf16x8*)(brow + (g * 64) * WLDS_ROWP + ks * 32);
                        acc[g] = __builtin_amdgcn_mfma_f32_16x16x32_bf16(a, b, acc[g], 0, 0, 0);
                    }
                }
            }
        }

        // ---- E: epilogue; tagged pub FIRST (latency overlaps the rest) ----
        u32* pub = exch + ((size_t)bid * 2 + cur) * 1024;
        const u32 tagv = (u32)(t + 1) << 16;
        float hv[4];
#pragma unroll
        for (int r = 0; r < 4; ++r) {
            float gi = sigmoid_f(acc[0][r]);
            float gf = sigmoid_f(acc[1][r]);
            float gg = tanh_f(acc[2][r]);
            float go = sigmoid_f(acc[3][r]);
            float c  = gf * c_st[r] + gi * gg;
            c_st[r]  = c;
            float h  = go * tanh_f(c);
            hv[r]    = h;
            bf16_t hb = (bf16_t)h;
            const int row = kb * 4 + r;
            const u32 word = (u32)__builtin_bit_cast(unsigned short, hb) | tagv;
            __hip_atomic_store(pub + row * 64 + jblk, word,
                               __ATOMIC_RELAXED, __HIP_MEMORY_SCOPE_SYSTEM);
            hnxt[row * 328 + jglob] = hb;                  // own A for next step
        }
        __syncthreads();                                   // B0: hxx[nxt] ready

        // ---- F: out stores (off the critical path) ----
#pragma unroll
        for (int r = 0; r < 4; ++r) {
            const int row = kb * 4 + r;
            const int bg  = group * 16 + row;
            out[((size_t)bg * TSTEPS + t) * HID + jglob] = hv[r];
        }
        if (t == TSTEPS - 1) {
            float* hn = out + (size_t)BATCH * TSTEPS * HID;
            float* cn = hn + (size_t)BATCH * HID;
#pragma unroll
            for (int r = 0; r < 4; ++r) {
                const int row = kb * 4 + r;
                const int bg  = group * 16 + row;
                hn[(size_t)bg * HID + jglob] = hv[r];
                cn[(size_t)bg * HID + jglob] = c_st[r];
            }
        }
    }
}

extern "C" void kernel_launch(void* const* d_in, const int* in_sizes, int n_in,
                              void* d_out, int out_size, void* d_ws, size_t ws_size,
                              hipStream_t stream)
{
    (void)in_sizes; (void)n_in; (void)out_size; (void)ws_size;
    const float* x   = (const float*)d_in[0];
    const float* Wii = (const float*)d_in[1];
    const float* bii = (const float*)d_in[2];
    const float* Wif = (const float*)d_in[3];
    const float* bif = (const float*)d_in[4];
    const float* Wig = (const float*)d_in[5];
    const float* big = (const float*)d_in[6];
    const float* Wio = (const float*)d_in[7];
    const float* bio = (const float*)d_in[8];
    const float* Whi = (const float*)d_in[9];
    const float* bhi = (const float*)d_in[10];
    const float* Whf = (const float*)d_in[11];
    const float* bhf = (const float*)d_in[12];
    const float* Whg = (const float*)d_in[13];
    const float* bhg = (const float*)d_in[14];
    const float* Who = (const float*)d_in[15];
    const float* bho = (const float*)d_in[16];

    char* ws = (char*)d_ws;
    bf16_t* wpack = (bf16_t*)(ws + WPACK_OFF);
    float*  bias  = (float*)(ws + BIAS_OFF);
    u32*    exch  = (u32*)(ws + EXCH_OFF);

    static bool attr_set = false;
    if (!attr_set) {
        (void)hipFuncSetAttribute(reinterpret_cast<const void*>(lstm_main),
                                  hipFuncAttributeMaxDynamicSharedMemorySize,
                                  SMEM_BYTES);
        attr_set = true;
    }

    lstm_prep<<<(1024 * KTOT + 255) / 256, 256, 0, stream>>>(
        Wii, Wif, Wig, Wio, Whi, Whf, Whg, Who,
        bii, bif, big, bio, bhi, bhf, bhg, bho,
        wpack, bias, exch);

    lstm_main<<<32, 256, SMEM_BYTES, stream>>>(
        x, wpack, bias, (float*)d_out, exch);
}